// Round 1
// baseline (101.402 us; speedup 1.0000x reference)
//
#include <hip/hip_runtime.h>

// Input:  x (8, 32, 512, 512) fp32  -> 256 images of 512x512
// Output: LL,LH,HL,HH each (8, 32, 256, 256) fp32, concatenated flat.
//
// Per thread: 2 input rows x 8 cols (4x float4 loads) -> 4 output cols
// in each of the 4 planes (4x float4 stores). Pure memory-bound.

#define N_IMG   256u                  // 8*32
#define IN_W    512u
#define OUT_W   256u
#define PLANE   (N_IMG * OUT_W * OUT_W)   // 16,777,216 elements per output plane

__global__ __launch_bounds__(256) void dwt2d_haar_kernel(
    const float* __restrict__ x, float* __restrict__ out)
{
    unsigned t = blockIdx.x * 256u + threadIdx.x;
    // per image: 256 output rows * 64 quad-col groups = 16384 threads
    unsigned img = t >> 14;
    unsigned rem = t & 16383u;
    unsigned i   = rem >> 6;       // output row 0..255
    unsigned g   = rem & 63u;      // quad-col group 0..63 (input cols 8g..8g+7)

    const float* rowbase = x + (size_t)img * (IN_W * IN_W)
                             + (size_t)(2u * i) * IN_W + 8u * g;

    float4 r0a = *reinterpret_cast<const float4*>(rowbase);
    float4 r0b = *reinterpret_cast<const float4*>(rowbase + 4);
    float4 r1a = *reinterpret_cast<const float4*>(rowbase + IN_W);
    float4 r1b = *reinterpret_cast<const float4*>(rowbase + IN_W + 4);

    float4 ll, lh, hl, hh;

    // column 0: x00=r0a.x x01=r0a.y x10=r1a.x x11=r1a.y
    ll.x = (r0a.x + r0a.y + r1a.x + r1a.y) * 0.5f;
    lh.x = (r0a.x + r0a.y - r1a.x - r1a.y) * 0.5f;
    hl.x = (r0a.x - r0a.y + r1a.x - r1a.y) * 0.5f;
    hh.x = (r0a.x - r0a.y - r1a.x + r1a.y) * 0.5f;
    // column 1: r0a.z/r0a.w, r1a.z/r1a.w
    ll.y = (r0a.z + r0a.w + r1a.z + r1a.w) * 0.5f;
    lh.y = (r0a.z + r0a.w - r1a.z - r1a.w) * 0.5f;
    hl.y = (r0a.z - r0a.w + r1a.z - r1a.w) * 0.5f;
    hh.y = (r0a.z - r0a.w - r1a.z + r1a.w) * 0.5f;
    // column 2: r0b.x/r0b.y, r1b.x/r1b.y
    ll.z = (r0b.x + r0b.y + r1b.x + r1b.y) * 0.5f;
    lh.z = (r0b.x + r0b.y - r1b.x - r1b.y) * 0.5f;
    hl.z = (r0b.x - r0b.y + r1b.x - r1b.y) * 0.5f;
    hh.z = (r0b.x - r0b.y - r1b.x + r1b.y) * 0.5f;
    // column 3: r0b.z/r0b.w, r1b.z/r1b.w
    ll.w = (r0b.z + r0b.w + r1b.z + r1b.w) * 0.5f;
    lh.w = (r0b.z + r0b.w - r1b.z - r1b.w) * 0.5f;
    hl.w = (r0b.z - r0b.w + r1b.z - r1b.w) * 0.5f;
    hh.w = (r0b.z - r0b.w - r1b.z + r1b.w) * 0.5f;

    size_t oidx = (size_t)img * (OUT_W * OUT_W) + (size_t)i * OUT_W + 4u * g;
    *reinterpret_cast<float4*>(out + 0ull * PLANE + oidx) = ll;
    *reinterpret_cast<float4*>(out + 1ull * PLANE + oidx) = lh;
    *reinterpret_cast<float4*>(out + 2ull * PLANE + oidx) = hl;
    *reinterpret_cast<float4*>(out + 3ull * PLANE + oidx) = hh;
}

extern "C" void kernel_launch(void* const* d_in, const int* in_sizes, int n_in,
                              void* d_out, int out_size, void* d_ws, size_t ws_size,
                              hipStream_t stream) {
    const float* x = (const float*)d_in[0];
    float* out = (float*)d_out;
    // total threads = 256 images * 16384 = 4,194,304 -> 16384 blocks of 256
    dim3 grid(16384), block(256);
    hipLaunchKernelGGL(dwt2d_haar_kernel, grid, block, 0, stream, x, out);
}